// Round 3
// baseline (175.151 us; speedup 1.0000x reference)
//
#include <hip/hip_runtime.h>
#include <math.h>

typedef _Float16 h4  __attribute__((ext_vector_type(4)));
typedef _Float16 h8  __attribute__((ext_vector_type(8)));
typedef float    f4  __attribute__((ext_vector_type(4)));
typedef float    f32x4 __attribute__((ext_vector_type(4)));

#define W1_ELEMS (384*128)
#define W2_ELEMS (128*128)
#define BM_ELEMS (4*64*64)
#define LOG2E 1.44269504088896340736f

// w1 rows permuted to (kind, head, e)-major: wave wv's A-fragments are exactly
// head wv's Q, K, V channels. Also precompute the 4 bias+mask variants
// (rowmask x colmask), scaled by log2e for exp2-base softmax.
__global__ void cvt_weights(const float* __restrict__ w1, const float* __restrict__ w2,
                            const float* __restrict__ rel_bias,
                            _Float16* __restrict__ w1h, _Float16* __restrict__ w2h,
                            _Float16* __restrict__ bmg) {
    int i = blockIdx.x * 256 + threadIdx.x;
    if (i < W1_ELEMS) {
        int j = i >> 7, k = i & 127;
        int c = j / 3;
        int kind = j - 3 * c;
        int jp = kind * 128 + (c & 7) * 16 + (c >> 3);
        w1h[jp * 128 + k] = (_Float16)w1[i];
    }
    if (i < W2_ELEMS) w2h[i] = (_Float16)w2[i];
    if (i < BM_ELEMS) {
        int v = i >> 12, f = i & 4095;
        int ti = f >> 6, tj = f & 63;          // ti = query token, tj = key token
        float val = rel_bias[((ti >> 3) - (tj >> 3) + 7) * 15 + ((ti & 7) - (tj & 7) + 7)] * LOG2E;
        if ((v & 2) && ((ti ^ tj) & 32)) val = -INFINITY;
        if ((v & 1) && ((ti ^ tj) & 4))  val = -INFINITY;
        bmg[i] = (_Float16)val;
    }
}

// One block per (batch, window). 512 threads = 8 waves; wave wv owns head wv.
// Q,K,V live entirely in registers (MFMA D-layout == fragment layout via
// operand-order choice). LDS: xh (input tile) + Ob (attention output) = 34 KB.
__global__ __launch_bounds__(512, 4)
void swin_fused(const float* __restrict__ x,
                const float* __restrict__ b1,
                const float* __restrict__ b2,
                const _Float16* __restrict__ w1h,
                const _Float16* __restrict__ w2h,
                const _Float16* __restrict__ bmg,
                float* __restrict__ out)
{
    __shared__ _Float16 xh[64*136];   // staged fp16 input tile [token][ch]
    __shared__ _Float16 Ob[64*136];   // attention output tile  [token][ch]

    const int tid  = threadIdx.x;
    const int lane = tid & 63;
    const int wv   = tid >> 6;       // wave id == head
    const int quad = lane >> 4;      // 0..3
    const int l16  = lane & 15;

    const int blk = blockIdx.x;
    const int b   = blk >> 6;
    const int Hw  = (blk >> 3) & 7;
    const int Ww  = blk & 7;

    // ---- Phase 0: gather shifted x rows -> fp16 LDS --------------------------
    {
        const int r0 = tid >> 5;        // 0..15
        const int c4 = tid & 31;        // float4 column
        #pragma unroll
        for (int it = 0; it < 4; ++it) {
            int t  = r0 + it*16;                      // token 0..63
            int gi = (Hw*8 + (t >> 3) + 4) & 63;      // shifted source row
            int gj = (Ww*8 + (t & 7) + 4) & 63;
            f32x4 v = *(const f32x4*)(x + ((size_t)b*4096 + gi*64 + gj)*128 + c4*4);
            h4 hv;
            hv[0] = (_Float16)v[0]; hv[1] = (_Float16)v[1];
            hv[2] = (_Float16)v[2]; hv[3] = (_Float16)v[3];
            *(h4*)(&xh[t*136 + c4*4]) = hv;
        }
    }

    // per-lane biases (original w1 row for (kind,h,e) = 24*e + 3*h + kind)
    float bQ[4], bK[4];
    #pragma unroll
    for (int r = 0; r < 4; ++r) {
        bQ[r] = b1[24*(quad*4 + r) + 3*wv + 0];
        bK[r] = b1[24*(quad*4 + r) + 3*wv + 1];
    }
    const float bV = b1[24*l16 + 3*wv + 2];

    __syncthreads();

    // ---- Phase 1: QKV projection for head wv ---------------------------------
    // accQ/accK: D[m=e on (quad,reg)][n=tok on l16]  (A = w1 rows, B = x)
    // accV     : D[m=tok on (quad,reg)][n=e on l16]  (A = x, B = w1 rows) -- swapped!
    f4 accQ[4], accK[4], accV[4];
    #pragma unroll
    for (int tt = 0; tt < 4; ++tt) {
        accQ[tt] = (f4){0.f,0.f,0.f,0.f};
        accK[tt] = (f4){0.f,0.f,0.f,0.f};
        accV[tt] = (f4){0.f,0.f,0.f,0.f};
    }
    for (int kb = 0; kb < 4; ++kb) {
        h8 bfx[4];   // x tokens: [tok on l16][inch on quad*8+reg]
        #pragma unroll
        for (int tt = 0; tt < 4; ++tt)
            bfx[tt] = *(const h8*)(&xh[(tt*16 + l16)*136 + kb*32 + quad*8]);
        h8 aQ = *(const h8*)(w1h + (size_t)((0*8 + wv)*16 + l16)*128 + kb*32 + quad*8);
        h8 aK = *(const h8*)(w1h + (size_t)((1*8 + wv)*16 + l16)*128 + kb*32 + quad*8);
        h8 aV = *(const h8*)(w1h + (size_t)((2*8 + wv)*16 + l16)*128 + kb*32 + quad*8);
        #pragma unroll
        for (int tt = 0; tt < 4; ++tt) {
            accQ[tt] = __builtin_amdgcn_mfma_f32_16x16x32_f16(aQ, bfx[tt], accQ[tt], 0, 0, 0);
            accK[tt] = __builtin_amdgcn_mfma_f32_16x16x32_f16(aK, bfx[tt], accK[tt], 0, 0, 0);
            accV[tt] = __builtin_amdgcn_mfma_f32_16x16x32_f16(bfx[tt], aV, accV[tt], 0, 0, 0);
        }
    }

    // ---- Phase 2: attention for head wv (all fragments register-renamed) -----
    {
        const _Float16* bmp = bmg + ((((Hw == 7) ? 2 : 0) | ((Ww == 7) ? 1 : 0)) << 12);
        const float qsc = 0.25f * LOG2E;     // 1/sqrt(16) * log2e

        // K A-fragments: ak[mt][i] = K[j = mt*16+l16][e = quad*4+i]
        h4 ak[4];
        #pragma unroll
        for (int mt = 0; mt < 4; ++mt)
            #pragma unroll
            for (int r = 0; r < 4; ++r)
                ak[mt][r] = (_Float16)(accK[mt][r] + bK[r]);
        // V^T A-fragments: av[kt][i] = V[j = kt*16+quad*4+i][e = l16]
        h4 av[4];
        #pragma unroll
        for (int kt = 0; kt < 4; ++kt)
            #pragma unroll
            for (int r = 0; r < 4; ++r)
                av[kt][r] = (_Float16)(accV[kt][r] + bV);

        for (int nt = 0; nt < 4; ++nt) {
            // Q^T B-fragment: bq[i] = Q[e = quad*4+i][tok = nt*16+l16], pre-scaled
            h4 bq;
            #pragma unroll
            for (int i = 0; i < 4; ++i)
                bq[i] = (_Float16)((accQ[nt][i] + bQ[i]) * qsc);

            // T = S^T tiles: D row = key j, col = query i
            f4 T[4];
            #pragma unroll
            for (int mt = 0; mt < 4; ++mt) {
                f4 z = {0.f,0.f,0.f,0.f};
                T[mt] = __builtin_amdgcn_mfma_f32_16x16x16f16(ak[mt], bq, z, 0, 0, 0);
            }
            // bias+mask from global (L1-resident 8KB variant)
            #pragma unroll
            for (int mt = 0; mt < 4; ++mt) {
                h4 bmv = *(const h4*)(bmp + (nt*16 + l16)*64 + mt*16 + quad*4);
                #pragma unroll
                for (int r = 0; r < 4; ++r)
                    T[mt][r] += (float)bmv[r];
            }

            // softmax over keys j (exp2 base; log2e folded into Q-scale and bias)
            float m = -INFINITY;
            #pragma unroll
            for (int mt = 0; mt < 4; ++mt)
                #pragma unroll
                for (int r = 0; r < 4; ++r) m = fmaxf(m, T[mt][r]);
            m = fmaxf(m, __shfl_xor(m, 16, 64));
            m = fmaxf(m, __shfl_xor(m, 32, 64));
            float s = 0.f;
            h4 P[4];
            #pragma unroll
            for (int mt = 0; mt < 4; ++mt)
                #pragma unroll
                for (int r = 0; r < 4; ++r) {
                    float p = __builtin_amdgcn_exp2f(T[mt][r] - m);
                    s += p;
                    P[mt][r] = (_Float16)p;
                }
            s += __shfl_xor(s, 16, 64);
            s += __shfl_xor(s, 32, 64);
            float rcp = 1.0f / s;

            // O^T tile: m = e, n = query i, k = j
            f4 o = {0.f,0.f,0.f,0.f};
            #pragma unroll
            for (int kt = 0; kt < 4; ++kt)
                o = __builtin_amdgcn_mfma_f32_16x16x16f16(av[kt], P[kt], o, 0, 0, 0);
            h4 ov;
            #pragma unroll
            for (int r = 0; r < 4; ++r) ov[r] = (_Float16)(o[r] * rcp);
            // O[token][ch = wv*16 + quad*4 + r]
            *(h4*)(&Ob[(nt*16 + l16)*136 + wv*16 + quad*4]) = ov;
        }
    }
    __syncthreads();   // all heads' O must land before the output projection

    // ---- Phase 3: output projection (64x128, K=128), 1 N-tile per wave -------
    {
        h8 af[4][4];
        #pragma unroll
        for (int mt = 0; mt < 4; ++mt)
            #pragma unroll
            for (int kb = 0; kb < 4; ++kb)
                af[mt][kb] = *(const h8*)(&Ob[(mt*16 + l16)*136 + kb*32 + quad*8]);

        const int o = wv*16 + l16;            // output channel
        f4 acc3[4] = {{0.f,0.f,0.f,0.f},{0.f,0.f,0.f,0.f},{0.f,0.f,0.f,0.f},{0.f,0.f,0.f,0.f}};
        for (int kb = 0; kb < 4; ++kb) {
            h8 bf = *(const h8*)(w2h + (size_t)o*128 + kb*32 + quad*8);
            #pragma unroll
            for (int mt = 0; mt < 4; ++mt)
                acc3[mt] = __builtin_amdgcn_mfma_f32_16x16x32_f16(af[mt][kb], bf, acc3[mt], 0, 0, 0);
        }
        float bias = b2[o];
        #pragma unroll
        for (int mt = 0; mt < 4; ++mt) {
            #pragma unroll
            for (int r = 0; r < 4; ++r) {
                int t  = mt*16 + quad*4 + r;
                int gi = Hw*8 + (t >> 3);
                int gj = Ww*8 + (t & 7);
                out[((size_t)b*4096 + gi*64 + gj)*128 + o] = acc3[mt][r] + bias;
            }
        }
    }
}

extern "C" void kernel_launch(void* const* d_in, const int* in_sizes, int n_in,
                              void* d_out, int out_size, void* d_ws, size_t ws_size,
                              hipStream_t stream) {
    (void)in_sizes; (void)n_in; (void)out_size; (void)ws_size;
    const float* x  = (const float*)d_in[0];
    const float* w1 = (const float*)d_in[1];
    const float* b1 = (const float*)d_in[2];
    const float* w2 = (const float*)d_in[3];
    const float* b2 = (const float*)d_in[4];
    const float* rb = (const float*)d_in[5];

    _Float16* w1h = (_Float16*)d_ws;
    _Float16* w2h = (_Float16*)((char*)d_ws + (size_t)W1_ELEMS * sizeof(_Float16));
    _Float16* bmg = (_Float16*)((char*)d_ws + (size_t)(W1_ELEMS + W2_ELEMS) * sizeof(_Float16));
    float* outp = (float*)d_out;

    cvt_weights<<<(W1_ELEMS + 255)/256, 256, 0, stream>>>(w1, w2, rb, w1h, w2h, bmg);
    swin_fused<<<32*64, 512, 0, stream>>>(x, b1, b2, w1h, w2h, bmg, outp);
}

// Round 4
// 152.799 us; speedup vs baseline: 1.1463x; 1.1463x over previous
//
#include <hip/hip_runtime.h>
#include <math.h>

typedef _Float16 h4  __attribute__((ext_vector_type(4)));
typedef _Float16 h8  __attribute__((ext_vector_type(8)));
typedef float    f4  __attribute__((ext_vector_type(4)));
typedef float    f32x4 __attribute__((ext_vector_type(4)));

#define W1_ELEMS (384*128)
#define W2_ELEMS (128*128)
#define BM_ELEMS (4*64*64)
#define LOG2E 1.44269504088896340736f

// w1 rows permuted to (kind, head, e)-major: wave wv's A-fragments are exactly
// head wv's Q, K, V channels. Also precompute the 4 bias+mask variants
// (rowmask x colmask), scaled by log2e for exp2-base softmax.
__global__ void cvt_weights(const float* __restrict__ w1, const float* __restrict__ w2,
                            const float* __restrict__ rel_bias,
                            _Float16* __restrict__ w1h, _Float16* __restrict__ w2h,
                            _Float16* __restrict__ bmg) {
    int i = blockIdx.x * 256 + threadIdx.x;
    if (i < W1_ELEMS) {
        int j = i >> 7, k = i & 127;
        int c = j / 3;
        int kind = j - 3 * c;
        int jp = kind * 128 + (c & 7) * 16 + (c >> 3);
        w1h[jp * 128 + k] = (_Float16)w1[i];
    }
    if (i < W2_ELEMS) w2h[i] = (_Float16)w2[i];
    if (i < BM_ELEMS) {
        int v = i >> 12, f = i & 4095;
        int ti = f >> 6, tj = f & 63;          // ti = query token, tj = key token
        float val = rel_bias[((ti >> 3) - (tj >> 3) + 7) * 15 + ((ti & 7) - (tj & 7) + 7)] * LOG2E;
        if ((v & 2) && ((ti ^ tj) & 32)) val = -INFINITY;
        if ((v & 1) && ((ti ^ tj) & 4))  val = -INFINITY;
        bmg[i] = (_Float16)val;
    }
}

// One block per (batch, window). 512 threads = 8 waves; wave wv owns head wv.
// Q,K,V live entirely in registers; converted to f16 fragments IMMEDIATELY
// after phase 1 so the 48-f32 accumulator live range ends before softmax.
// bm is a plain LDS copy of the precomputed global table (8.5 KB).
__global__ __launch_bounds__(512, 4)
void swin_fused(const float* __restrict__ x,
                const float* __restrict__ b1,
                const float* __restrict__ b2,
                const _Float16* __restrict__ w1h,
                const _Float16* __restrict__ w2h,
                const _Float16* __restrict__ bmg,
                float* __restrict__ out)
{
    __shared__ _Float16 xh[64*136];   // staged fp16 input tile [token][ch]
    __shared__ _Float16 Ob[64*136];   // attention output tile  [token][ch]
    __shared__ _Float16 bm[64*68];    // [query i][key j] bias*log2e + mask

    const int tid  = threadIdx.x;
    const int lane = tid & 63;
    const int wv   = tid >> 6;       // wave id == head
    const int quad = lane >> 4;      // 0..3
    const int l16  = lane & 15;

    const int blk = blockIdx.x;
    const int b   = blk >> 6;
    const int Hw  = (blk >> 3) & 7;
    const int Ww  = blk & 7;

    // ---- Phase 0a: bm copy (global -> LDS), latency hides under 0b ----------
    {
        const int variant = (((Hw == 7) ? 2 : 0) | ((Ww == 7) ? 1 : 0));
        const int i = tid >> 3;          // row (query token) 0..63
        const int c = (tid & 7) * 8;     // col block
        h8 v = *(const h8*)(bmg + (variant << 12) + i*64 + c);
        *(h8*)(&bm[i*68 + c]) = v;
    }
    // ---- Phase 0b: gather shifted x rows -> fp16 LDS -------------------------
    {
        const int r0 = tid >> 5;        // 0..15
        const int c4 = tid & 31;        // float4 column
        #pragma unroll
        for (int it = 0; it < 4; ++it) {
            int t  = r0 + it*16;                      // token 0..63
            int gi = (Hw*8 + (t >> 3) + 4) & 63;      // shifted source row
            int gj = (Ww*8 + (t & 7) + 4) & 63;
            f32x4 v = *(const f32x4*)(x + ((size_t)b*4096 + gi*64 + gj)*128 + c4*4);
            h4 hv;
            hv[0] = (_Float16)v[0]; hv[1] = (_Float16)v[1];
            hv[2] = (_Float16)v[2]; hv[3] = (_Float16)v[3];
            *(h4*)(&xh[t*136 + c4*4]) = hv;
        }
    }

    // per-lane biases (original w1 row for (kind,h,e) = 24*e + 3*h + kind)
    float bQ[4], bK[4];
    #pragma unroll
    for (int r = 0; r < 4; ++r) {
        bQ[r] = b1[24*(quad*4 + r) + 3*wv + 0];
        bK[r] = b1[24*(quad*4 + r) + 3*wv + 1];
    }
    const float bV = b1[24*l16 + 3*wv + 2];

    __syncthreads();

    // ---- Phase 1: QKV projection for head wv; fragments built in-place -------
    // accQ/accK: D[m=e on (quad,reg)][n=tok on l16]  (A = w1 rows, B = x)
    // accV     : D[m=tok on (quad,reg)][n=e on l16]  (A = x, B = w1 rows) -- swapped!
    h4 ak[4], av[4], qb[4];
    {
        f4 accQ[4], accK[4], accV[4];
        #pragma unroll
        for (int tt = 0; tt < 4; ++tt) {
            accQ[tt] = (f4){0.f,0.f,0.f,0.f};
            accK[tt] = (f4){0.f,0.f,0.f,0.f};
            accV[tt] = (f4){0.f,0.f,0.f,0.f};
        }
        for (int kb = 0; kb < 4; ++kb) {
            h8 bfx[4];   // x tokens: [tok on l16][inch on quad*8+reg]
            #pragma unroll
            for (int tt = 0; tt < 4; ++tt)
                bfx[tt] = *(const h8*)(&xh[(tt*16 + l16)*136 + kb*32 + quad*8]);
            h8 aQ = *(const h8*)(w1h + (size_t)((0*8 + wv)*16 + l16)*128 + kb*32 + quad*8);
            h8 aK = *(const h8*)(w1h + (size_t)((1*8 + wv)*16 + l16)*128 + kb*32 + quad*8);
            h8 aV = *(const h8*)(w1h + (size_t)((2*8 + wv)*16 + l16)*128 + kb*32 + quad*8);
            #pragma unroll
            for (int tt = 0; tt < 4; ++tt) {
                accQ[tt] = __builtin_amdgcn_mfma_f32_16x16x32_f16(aQ, bfx[tt], accQ[tt], 0, 0, 0);
                accK[tt] = __builtin_amdgcn_mfma_f32_16x16x32_f16(aK, bfx[tt], accK[tt], 0, 0, 0);
                accV[tt] = __builtin_amdgcn_mfma_f32_16x16x32_f16(bfx[tt], aV, accV[tt], 0, 0, 0);
            }
        }
        // Immediate conversion: ends the 48-f32 live range here.
        const float qsc = 0.25f * LOG2E;     // 1/sqrt(16) * log2e
        #pragma unroll
        for (int mt = 0; mt < 4; ++mt)
            #pragma unroll
            for (int r = 0; r < 4; ++r) {
                ak[mt][r] = (_Float16)( accK[mt][r] + bK[r]);          // K[j=mt*16+l16][e=quad*4+r]
                av[mt][r] = (_Float16)( accV[mt][r] + bV);             // V[j=mt*16+quad*4+r][e=l16]
                qb[mt][r] = (_Float16)((accQ[mt][r] + bQ[r]) * qsc);   // Q[e=quad*4+r][tok=mt*16+l16]
            }
    }

    // ---- Phase 2: attention for head wv --------------------------------------
    for (int nt = 0; nt < 4; ++nt) {
        // T = S^T tiles: D row = key j, col = query i
        f4 T[4];
        #pragma unroll
        for (int mt = 0; mt < 4; ++mt) {
            f4 z = {0.f,0.f,0.f,0.f};
            T[mt] = __builtin_amdgcn_mfma_f32_16x16x16f16(ak[mt], qb[nt], z, 0, 0, 0);
        }
        // bias+mask from LDS
        #pragma unroll
        for (int mt = 0; mt < 4; ++mt) {
            h4 bmv = *(const h4*)(&bm[(nt*16 + l16)*68 + mt*16 + quad*4]);
            #pragma unroll
            for (int r = 0; r < 4; ++r)
                T[mt][r] += (float)bmv[r];
        }

        // softmax over keys j (exp2 base; log2e folded into Q-scale and bias)
        float m = -INFINITY;
        #pragma unroll
        for (int mt = 0; mt < 4; ++mt)
            #pragma unroll
            for (int r = 0; r < 4; ++r) m = fmaxf(m, T[mt][r]);
        m = fmaxf(m, __shfl_xor(m, 16, 64));
        m = fmaxf(m, __shfl_xor(m, 32, 64));
        float s = 0.f;
        h4 P[4];
        #pragma unroll
        for (int mt = 0; mt < 4; ++mt)
            #pragma unroll
            for (int r = 0; r < 4; ++r) {
                float p = __builtin_amdgcn_exp2f(T[mt][r] - m);
                s += p;
                P[mt][r] = (_Float16)p;
            }
        s += __shfl_xor(s, 16, 64);
        s += __shfl_xor(s, 32, 64);
        float rcp = 1.0f / s;

        // O^T tile: m = e, n = query i, k = j
        f4 o = {0.f,0.f,0.f,0.f};
        #pragma unroll
        for (int kt = 0; kt < 4; ++kt)
            o = __builtin_amdgcn_mfma_f32_16x16x16f16(av[kt], P[kt], o, 0, 0, 0);
        h4 ov;
        #pragma unroll
        for (int r = 0; r < 4; ++r) ov[r] = (_Float16)(o[r] * rcp);
        // O[token][ch = wv*16 + quad*4 + r]
        *(h4*)(&Ob[(nt*16 + l16)*136 + wv*16 + quad*4]) = ov;
    }
    __syncthreads();   // all heads' O must land before the output projection

    // ---- Phase 3: output projection (64x128, K=128), 1 N-tile per wave -------
    {
        h8 af[4][4];
        #pragma unroll
        for (int mt = 0; mt < 4; ++mt)
            #pragma unroll
            for (int kb = 0; kb < 4; ++kb)
                af[mt][kb] = *(const h8*)(&Ob[(mt*16 + l16)*136 + kb*32 + quad*8]);

        const int o = wv*16 + l16;            // output channel
        f4 acc3[4] = {{0.f,0.f,0.f,0.f},{0.f,0.f,0.f,0.f},{0.f,0.f,0.f,0.f},{0.f,0.f,0.f,0.f}};
        for (int kb = 0; kb < 4; ++kb) {
            h8 bf = *(const h8*)(w2h + (size_t)o*128 + kb*32 + quad*8);
            #pragma unroll
            for (int mt = 0; mt < 4; ++mt)
                acc3[mt] = __builtin_amdgcn_mfma_f32_16x16x32_f16(af[mt][kb], bf, acc3[mt], 0, 0, 0);
        }
        float bias = b2[o];
        #pragma unroll
        for (int mt = 0; mt < 4; ++mt) {
            #pragma unroll
            for (int r = 0; r < 4; ++r) {
                int t  = mt*16 + quad*4 + r;
                int gi = Hw*8 + (t >> 3);
                int gj = Ww*8 + (t & 7);
                out[((size_t)b*4096 + gi*64 + gj)*128 + o] = acc3[mt][r] + bias;
            }
        }
    }
}

extern "C" void kernel_launch(void* const* d_in, const int* in_sizes, int n_in,
                              void* d_out, int out_size, void* d_ws, size_t ws_size,
                              hipStream_t stream) {
    (void)in_sizes; (void)n_in; (void)out_size; (void)ws_size;
    const float* x  = (const float*)d_in[0];
    const float* w1 = (const float*)d_in[1];
    const float* b1 = (const float*)d_in[2];
    const float* w2 = (const float*)d_in[3];
    const float* b2 = (const float*)d_in[4];
    const float* rb = (const float*)d_in[5];

    _Float16* w1h = (_Float16*)d_ws;
    _Float16* w2h = (_Float16*)((char*)d_ws + (size_t)W1_ELEMS * sizeof(_Float16));
    _Float16* bmg = (_Float16*)((char*)d_ws + (size_t)(W1_ELEMS + W2_ELEMS) * sizeof(_Float16));
    float* outp = (float*)d_out;

    cvt_weights<<<(W1_ELEMS + 255)/256, 256, 0, stream>>>(w1, w2, rb, w1h, w2h, bmg);
    swin_fused<<<32*64, 512, 0, stream>>>(x, b1, b2, w1h, w2h, bmg, outp);
}